// Round 5
// baseline (3137.526 us; speedup 1.0000x reference)
//
#include <hip/hip_runtime.h>
#include <cstdint>
#include <cstddef>

#define NDIM 8192
#define NITER 20
#define RPB 8               // rows per block
#define NBLK (NDIM / RPB)   // 1024 blocks / partial rows

// ---------- helpers ----------
__device__ __forceinline__ unsigned short f2bf_rne(float f) {
  unsigned int u = __float_as_uint(f);
  unsigned int r = 0x7fffu + ((u >> 16) & 1u);
  return (unsigned short)((u + r) >> 16);
}
__device__ __forceinline__ unsigned int pack2(float lo, float hi) {
  return (unsigned int)f2bf_rne(lo) | ((unsigned int)f2bf_rne(hi) << 16);
}
__device__ __forceinline__ float bflo(unsigned int u) { return __uint_as_float(u << 16); }
__device__ __forceinline__ float bfhi(unsigned int u) { return __uint_as_float(u & 0xffff0000u); }

// Block-wide reduction over 1024 threads for 8 rows. 2 barriers.
__device__ __forceinline__ void rows8_reduce(float (&dots)[8], float* ash,
                                             float* __restrict__ a_out, int i0) {
  const int t = threadIdx.x;
#pragma unroll
  for (int r = 0; r < 8; ++r)
#pragma unroll
    for (int m = 32; m >= 1; m >>= 1)
      dots[r] += __shfl_xor(dots[r], m, 64);
  __shared__ float red[16][8];
  const int w = t >> 6;
  if ((t & 63) == 0) {
#pragma unroll
    for (int r = 0; r < 8; ++r) red[w][r] = dots[r];
  }
  __syncthreads();
  if (t < 8) {
    float s = 0.0f;
#pragma unroll
    for (int ww = 0; ww < 16; ++ww) s += red[ww][t];
    float inv = 1.0f / s;
    ash[t] = inv;
    a_out[i0 + t] = inv;
  }
  __syncthreads();
}

// ---------- kernels ----------

// Iteration 1 fused with exp: read H, write E=bf16(exp(H)), a=1/rowsum (b==1),
// block-partial colsums. HBM-bound; 1 block/CU is fine.
__global__ __launch_bounds__(1024, 4) void k_first(const float* __restrict__ H,
                                                   unsigned short* __restrict__ E,
                                                   float* __restrict__ a,
                                                   float* __restrict__ partial) {
  const int t = threadIdx.x;
  const int j0 = t * 8;
  const int i0 = blockIdx.x * RPB;
  __shared__ float ash[8];

  uint4 cur[8];
  float dots[8];
#pragma unroll
  for (int r = 0; r < 8; ++r) {
    const float* hp = H + (size_t)(i0 + r) * NDIM + j0;
    float4 h0 = reinterpret_cast<const float4*>(hp)[0];
    float4 h1 = reinterpret_cast<const float4*>(hp)[1];
    float e0 = __expf(h0.x), e1 = __expf(h0.y), e2 = __expf(h0.z), e3 = __expf(h0.w);
    float e4 = __expf(h1.x), e5 = __expf(h1.y), e6 = __expf(h1.z), e7 = __expf(h1.w);
    cur[r] = uint4{pack2(e0, e1), pack2(e2, e3), pack2(e4, e5), pack2(e6, e7)};
    *reinterpret_cast<uint4*>(E + (size_t)(i0 + r) * NDIM + j0) = cur[r];
    dots[r] = ((e0 + e1) + (e2 + e3)) + ((e4 + e5) + (e6 + e7));
  }

  rows8_reduce(dots, ash, a, i0);

  float cs[8];
#pragma unroll
  for (int k = 0; k < 8; ++k) cs[k] = 0.0f;
#pragma unroll
  for (int r = 0; r < 8; ++r) {
    const float ai = ash[r];
    cs[0] += ai * bflo(cur[r].x); cs[1] += ai * bfhi(cur[r].x);
    cs[2] += ai * bflo(cur[r].y); cs[3] += ai * bfhi(cur[r].y);
    cs[4] += ai * bflo(cur[r].z); cs[5] += ai * bfhi(cur[r].z);
    cs[6] += ai * bflo(cur[r].w); cs[7] += ai * bfhi(cur[r].w);
  }
  float4* pp = reinterpret_cast<float4*>(partial + (size_t)blockIdx.x * NDIM + j0);
  pp[0] = float4{cs[0], cs[1], cs[2], cs[3]};
  pp[1] = float4{cs[4], cs[5], cs[6], cs[7]};
}

// Generic iteration: one E pass. Packed registers, transient b, 2 blocks/CU
// (64-VGPR budget) so a co-resident block covers the barrier/reduce phases.
__global__ __launch_bounds__(1024, 8) void k_iter(const unsigned short* __restrict__ E,
                                                  const float* __restrict__ b,
                                                  float* __restrict__ a,
                                                  float* __restrict__ partial) {
  const int t = threadIdx.x;
  const int j0 = t * 8;
  const int i0 = blockIdx.x * RPB;
  __shared__ float ash[8];

  const unsigned short* Eb = E + (size_t)i0 * NDIM + j0;
  uint4 cur[8];
#pragma unroll
  for (int r = 0; r < 8; ++r)
    cur[r] = *reinterpret_cast<const uint4*>(Eb + (size_t)r * NDIM);

  // transient b (dies before the reduce)
  const float4* bp = reinterpret_cast<const float4*>(b + j0);
  float4 b0 = bp[0], b1 = bp[1];

  float dots[8];
#pragma unroll
  for (int r = 0; r < 8; ++r) {
    dots[r] = ((bflo(cur[r].x) * b0.x + bfhi(cur[r].x) * b0.y) +
               (bflo(cur[r].y) * b0.z + bfhi(cur[r].y) * b0.w)) +
              ((bflo(cur[r].z) * b1.x + bfhi(cur[r].z) * b1.y) +
               (bflo(cur[r].w) * b1.z + bfhi(cur[r].w) * b1.w));
  }

  rows8_reduce(dots, ash, a, i0);

  float cs[8];
#pragma unroll
  for (int k = 0; k < 8; ++k) cs[k] = 0.0f;
#pragma unroll
  for (int r = 0; r < 8; ++r) {
    const float ai = ash[r];
    cs[0] += ai * bflo(cur[r].x); cs[1] += ai * bfhi(cur[r].x);
    cs[2] += ai * bflo(cur[r].y); cs[3] += ai * bfhi(cur[r].y);
    cs[4] += ai * bflo(cur[r].z); cs[5] += ai * bfhi(cur[r].z);
    cs[6] += ai * bflo(cur[r].w); cs[7] += ai * bfhi(cur[r].w);
  }
  float4* pp = reinterpret_cast<float4*>(partial + (size_t)blockIdx.x * NDIM + j0);
  pp[0] = float4{cs[0], cs[1], cs[2], cs[3]};
  pp[1] = float4{cs[4], cs[5], cs[6], cs[7]};
}

// b[j] = 1 / sum_{p<NBLK} partial[p][j]    (32MB read)
__global__ void k_colreduce(const float* __restrict__ partial, float* __restrict__ b) {
  const int j = blockIdx.x * blockDim.x + threadIdx.x;   // 32 blocks x 256 threads
  float s[8];
#pragma unroll
  for (int q = 0; q < 8; ++q) s[q] = 0.0f;
  for (int p = 0; p < NBLK; p += 8) {
#pragma unroll
    for (int q = 0; q < 8; ++q)
      s[q] += partial[(size_t)(p + q) * NDIM + j];
  }
  b[j] = 1.0f / (((s[0] + s[1]) + (s[2] + s[3])) + ((s[4] + s[5]) + (s[6] + s[7])));
}

// out[i][j] = E_bf16[i][j] * a[i] * b[j]   (E in workspace -> 384MB total)
__global__ void k_final_E(const unsigned short* __restrict__ E,
                          const float* __restrict__ a,
                          const float* __restrict__ b,
                          float* __restrict__ out) {
  const size_t nv = (size_t)NDIM * NDIM / 8;           // uint4 of 8 bf16
  const size_t stride = (size_t)gridDim.x * blockDim.x;
  for (size_t v = (size_t)blockIdx.x * blockDim.x + threadIdx.x; v < nv; v += stride) {
    uint4 ev = reinterpret_cast<const uint4*>(E)[v];
    const int i = (int)(v >> 10);                      // 1024 uint4 per row
    const int j8 = (int)(v & 1023) * 8;
    float4 bb0 = *reinterpret_cast<const float4*>(b + j8);
    float4 bb1 = *reinterpret_cast<const float4*>(b + j8 + 4);
    const float ai = a[i];
    float4 o0{bflo(ev.x) * ai * bb0.x, bfhi(ev.x) * ai * bb0.y,
              bflo(ev.y) * ai * bb0.z, bfhi(ev.y) * ai * bb0.w};
    float4 o1{bflo(ev.z) * ai * bb1.x, bfhi(ev.z) * ai * bb1.y,
              bflo(ev.w) * ai * bb1.z, bfhi(ev.w) * ai * bb1.w};
    float4* op = reinterpret_cast<float4*>(out + v * 8);
    op[0] = o0; op[1] = o1;
  }
}

// Fallback when workspace can't host E (E lives in d_out): recompute exp from H.
__global__ void k_final_H(const float* __restrict__ H,
                          const float* __restrict__ a,
                          const float* __restrict__ b,
                          float* __restrict__ out) {
  const size_t nv = (size_t)NDIM * NDIM / 4;
  const size_t stride = (size_t)gridDim.x * blockDim.x;
  for (size_t v = (size_t)blockIdx.x * blockDim.x + threadIdx.x; v < nv; v += stride) {
    float4 h = reinterpret_cast<const float4*>(H)[v];
    const int i = (int)(v >> 11);
    const int jv = (int)(v & 2047);
    float4 bb = reinterpret_cast<const float4*>(b)[jv];
    const float ai = a[i];
    float4 o;
    o.x = __expf(h.x) * ai * bb.x;
    o.y = __expf(h.y) * ai * bb.y;
    o.z = __expf(h.z) * ai * bb.z;
    o.w = __expf(h.w) * ai * bb.w;
    reinterpret_cast<float4*>(out)[v] = o;
  }
}

// ---------- launch ----------
extern "C" void kernel_launch(void* const* d_in, const int* in_sizes, int n_in,
                              void* d_out, int out_size, void* d_ws, size_t ws_size,
                              hipStream_t stream) {
  const float* H = (const float*)d_in[0];
  float* out = (float*)d_out;
  float* a = (float*)d_ws;                  // [NDIM] = 32KB
  float* b = a + NDIM;                      // [NDIM] = 32KB
  const size_t EBYTES = (size_t)NDIM * NDIM * 2;   // 128MB bf16

  unsigned short* E;
  float* partial;
  const bool ws_has_E = ws_size >= (size_t)64 * 1024 + EBYTES;
  if (ws_has_E) {
    E = (unsigned short*)((char*)d_ws + 64 * 1024);
    partial = (float*)d_out;                         // first 32MB of d_out
  } else {
    E = (unsigned short*)d_out;                      // first 128MB of d_out
    partial = (float*)((char*)d_out + EBYTES);       // next 32MB
  }

  // iteration 1 (b == 1), fused with exp
  k_first<<<NBLK, 1024, 0, stream>>>(H, E, a, partial);
  k_colreduce<<<NDIM / 256, 256, 0, stream>>>(partial, b);

  // iterations 2..20
  for (int it = 1; it < NITER; ++it) {
    k_iter<<<NBLK, 1024, 0, stream>>>(E, b, a, partial);
    k_colreduce<<<NDIM / 256, 256, 0, stream>>>(partial, b);
  }

  if (ws_has_E)
    k_final_E<<<2048, 256, 0, stream>>>(E, a, b, out);
  else
    k_final_H<<<2048, 256, 0, stream>>>(H, a, b, out);
}

// Round 6
// 2788.513 us; speedup vs baseline: 1.1252x; 1.1252x over previous
//
#include <hip/hip_runtime.h>
#include <cstdint>
#include <cstddef>

#define NDIM 8192
#define NITER 20

// ---------- helpers ----------
__device__ __forceinline__ unsigned short f2bf_rne(float f) {
  unsigned int u = __float_as_uint(f);
  unsigned int r = 0x7fffu + ((u >> 16) & 1u);
  return (unsigned short)((u + r) >> 16);
}
__device__ __forceinline__ unsigned int pack2(float lo, float hi) {
  return (unsigned int)f2bf_rne(lo) | ((unsigned int)f2bf_rne(hi) << 16);
}
__device__ __forceinline__ float bflo(unsigned int u) { return __uint_as_float(u << 16); }
__device__ __forceinline__ float bfhi(unsigned int u) { return __uint_as_float(u & 0xffff0000u); }

// Block-wide reduction over 1024 threads for 8 rows. 2 barriers.
// Writes 1/rowsum into ash[0..7] and a_out[i0..i0+7].
__device__ __forceinline__ void rows8_reduce(float (&dots)[8], float* ash,
                                             float* __restrict__ a_out, int i0) {
  const int t = threadIdx.x;
#pragma unroll
  for (int r = 0; r < 8; ++r)
#pragma unroll
    for (int m = 32; m >= 1; m >>= 1)
      dots[r] += __shfl_xor(dots[r], m, 64);
  __shared__ float red[16][8];
  const int w = t >> 6;
  if ((t & 63) == 0) {
#pragma unroll
    for (int r = 0; r < 8; ++r) red[w][r] = dots[r];
  }
  __syncthreads();
  if (t < 8) {
    float s = 0.0f;
#pragma unroll
    for (int ww = 0; ww < 16; ++ww) s += red[ww][t];
    float inv = 1.0f / s;
    ash[t] = inv;
    a_out[i0 + t] = inv;
  }
  __syncthreads();
}

// static-indexed building blocks for k_iter
__device__ __forceinline__ void load8(uint4 (&buf)[8], const unsigned short* Eb, int c) {
#pragma unroll
  for (int r = 0; r < 8; ++r)
    buf[r] = *reinterpret_cast<const uint4*>(Eb + (size_t)(c * 8 + r) * NDIM);
}
__device__ __forceinline__ void dots8(const uint4 (&buf)[8], const float4& b0,
                                      const float4& b1, float (&dots)[8]) {
#pragma unroll
  for (int r = 0; r < 8; ++r) {
    dots[r] = ((bflo(buf[r].x) * b0.x + bfhi(buf[r].x) * b0.y) +
               (bflo(buf[r].y) * b0.z + bfhi(buf[r].y) * b0.w)) +
              ((bflo(buf[r].z) * b1.x + bfhi(buf[r].z) * b1.y) +
               (bflo(buf[r].w) * b1.z + bfhi(buf[r].w) * b1.w));
  }
}
__device__ __forceinline__ void cs8(const uint4 (&buf)[8], const float* ash, float (&cs)[8]) {
#pragma unroll
  for (int r = 0; r < 8; ++r) {
    const float ai = ash[r];
    cs[0] += ai * bflo(buf[r].x); cs[1] += ai * bfhi(buf[r].x);
    cs[2] += ai * bflo(buf[r].y); cs[3] += ai * bfhi(buf[r].y);
    cs[4] += ai * bflo(buf[r].z); cs[5] += ai * bfhi(buf[r].z);
    cs[6] += ai * bflo(buf[r].w); cs[7] += ai * bfhi(buf[r].w);
  }
}

// ---------- kernels ----------

// Iteration 1 fused with exp (proven round-3 version): read H, write E,
// a = 1/rowsum (b==1), one partial row per 8-row block (1024 partial rows).
__global__ __launch_bounds__(1024) void k_first(const float* __restrict__ H,
                                                unsigned short* __restrict__ E,
                                                float* __restrict__ a,
                                                float* __restrict__ partial) {
  const int t = threadIdx.x;
  const int j0 = t * 8;
  const int i0 = blockIdx.x * 8;
  __shared__ float ash[8];

  uint4 cur[8];
  float dots[8];
#pragma unroll
  for (int r = 0; r < 8; ++r) {
    const float* hp = H + (size_t)(i0 + r) * NDIM + j0;
    float4 h0 = reinterpret_cast<const float4*>(hp)[0];
    float4 h1 = reinterpret_cast<const float4*>(hp)[1];
    float e0 = __expf(h0.x), e1 = __expf(h0.y), e2 = __expf(h0.z), e3 = __expf(h0.w);
    float e4 = __expf(h1.x), e5 = __expf(h1.y), e6 = __expf(h1.z), e7 = __expf(h1.w);
    cur[r] = uint4{pack2(e0, e1), pack2(e2, e3), pack2(e4, e5), pack2(e6, e7)};
    *reinterpret_cast<uint4*>(E + (size_t)(i0 + r) * NDIM + j0) = cur[r];
    dots[r] = ((e0 + e1) + (e2 + e3)) + ((e4 + e5) + (e6 + e7));
  }

  rows8_reduce(dots, ash, a, i0);

  float cs[8];
#pragma unroll
  for (int k = 0; k < 8; ++k) cs[k] = 0.0f;
  cs8(cur, ash, cs);

  float4* pp = reinterpret_cast<float4*>(partial + (size_t)blockIdx.x * NDIM + j0);
  pp[0] = float4{cs[0], cs[1], cs[2], cs[3]};
  pp[1] = float4{cs[4], cs[5], cs[6], cs[7]};
}

// Generic iteration: one E pass. 256 blocks x 32 rows (4 chunks of 8),
// named double-buffer (A/B) of packed bf16, cs accumulated across chunks,
// ONE partial row per block. No launch_bounds clamp -> no spills.
__global__ __launch_bounds__(1024) void k_iter(const unsigned short* __restrict__ E,
                                               const float* __restrict__ b,
                                               float* __restrict__ a,
                                               float* __restrict__ partial) {
  const int t = threadIdx.x;
  const int j0 = t * 8;
  const int i0 = blockIdx.x * 32;
  __shared__ float ash[8];

  const unsigned short* Eb = E + (size_t)i0 * NDIM + j0;

  const float4* bp = reinterpret_cast<const float4*>(b + j0);
  const float4 b0 = bp[0], b1 = bp[1];

  float cs[8];
#pragma unroll
  for (int k = 0; k < 8; ++k) cs[k] = 0.0f;

  uint4 A[8], B[8];
  float dots[8];

  load8(A, Eb, 0);
  load8(B, Eb, 1);           // 16 loads/wave outstanding at first wait

  // chunk 0 (A), prefetch chunk 2 into A after A dies
  dots8(A, b0, b1, dots);
  rows8_reduce(dots, ash, a, i0 + 0);
  cs8(A, ash, cs);
  load8(A, Eb, 2);

  // chunk 1 (B), prefetch chunk 3 into B
  dots8(B, b0, b1, dots);
  rows8_reduce(dots, ash, a, i0 + 8);
  cs8(B, ash, cs);
  load8(B, Eb, 3);

  // chunk 2 (A)
  dots8(A, b0, b1, dots);
  rows8_reduce(dots, ash, a, i0 + 16);
  cs8(A, ash, cs);

  // chunk 3 (B)
  dots8(B, b0, b1, dots);
  rows8_reduce(dots, ash, a, i0 + 24);
  cs8(B, ash, cs);

  float4* pp = reinterpret_cast<float4*>(partial + (size_t)blockIdx.x * NDIM + j0);
  pp[0] = float4{cs[0], cs[1], cs[2], cs[3]};
  pp[1] = float4{cs[4], cs[5], cs[6], cs[7]};
}

// b[j] = 1 / sum_{p<nrows} partial[p][j]
__global__ void k_colreduce(const float* __restrict__ partial, int nrows,
                            float* __restrict__ b) {
  const int j = blockIdx.x * blockDim.x + threadIdx.x;   // 32 blocks x 256 threads
  float s[8];
#pragma unroll
  for (int q = 0; q < 8; ++q) s[q] = 0.0f;
  for (int p = 0; p < nrows; p += 8) {
#pragma unroll
    for (int q = 0; q < 8; ++q)
      s[q] += partial[(size_t)(p + q) * NDIM + j];
  }
  b[j] = 1.0f / (((s[0] + s[1]) + (s[2] + s[3])) + ((s[4] + s[5]) + (s[6] + s[7])));
}

// out[i][j] = exp(H[i][j]) * a[i] * b[j]  (fp32; overwrites E/partial — dead)
__global__ void k_final(const float* __restrict__ H,
                        const float* __restrict__ a,
                        const float* __restrict__ b,
                        float* __restrict__ out) {
  const size_t nv = (size_t)NDIM * NDIM / 4;
  const size_t stride = (size_t)gridDim.x * blockDim.x;
  for (size_t v = (size_t)blockIdx.x * blockDim.x + threadIdx.x; v < nv; v += stride) {
    float4 h = reinterpret_cast<const float4*>(H)[v];
    const int i = (int)(v >> 11);
    const int jv = (int)(v & 2047);
    float4 bb = reinterpret_cast<const float4*>(b)[jv];
    const float ai = a[i];
    float4 o;
    o.x = __expf(h.x) * ai * bb.x;
    o.y = __expf(h.y) * ai * bb.y;
    o.z = __expf(h.z) * ai * bb.z;
    o.w = __expf(h.w) * ai * bb.w;
    reinterpret_cast<float4*>(out)[v] = o;
  }
}

// ---------- launch ----------
extern "C" void kernel_launch(void* const* d_in, const int* in_sizes, int n_in,
                              void* d_out, int out_size, void* d_ws, size_t ws_size,
                              hipStream_t stream) {
  const float* H = (const float*)d_in[0];
  float* out = (float*)d_out;
  unsigned short* E = (unsigned short*)d_out;                          // 128MB bf16
  float* partial = (float*)((char*)d_out + (size_t)NDIM * NDIM * 2);   // up to 32MB
  float* a = (float*)d_ws;                                             // [NDIM]
  float* b = a + NDIM;                                                 // [NDIM]

  // iteration 1 (b == 1), fused with exp; 1024 partial rows
  k_first<<<NDIM / 8, 1024, 0, stream>>>(H, E, a, partial);
  k_colreduce<<<NDIM / 256, 256, 0, stream>>>(partial, 1024, b);

  // iterations 2..20; 256 partial rows
  for (int it = 1; it < NITER; ++it) {
    k_iter<<<NDIM / 32, 1024, 0, stream>>>(E, b, a, partial);
    k_colreduce<<<NDIM / 256, 256, 0, stream>>>(partial, 256, b);
  }

  k_final<<<2048, 256, 0, stream>>>(H, a, b, out);
}